// Round 1
// baseline (1243.834 us; speedup 1.0000x reference)
//
#include <hip/hip_runtime.h>
#include <hip/hip_bf16.h>
#include <cstddef>

// Problem constants (from reference)
#define BB 128
#define SS 4096
#define HH 128
#define FF 256   // 2*H
#define N1 256
#define N2 64
#define ROWS 32  // rows per block; 32 | S so a block never crosses a batch b

// fp32 baseline: compute-bound on vector FMA (no fp32 MFMA on CDNA4).
// Structure: stage con tile in LDS -> register-tiled layer1 (8 rows x 4 cols
// per thread) -> h1 back to same LDS buffer -> layer2 (4 rows x 2 cols) ->
// cross-lane reduce + sigmoid.
__global__ __launch_bounds__(256, 4) void edge_mlp_f32(
    const float* __restrict__ nodes,   // [B,S,H]
    const float* __restrict__ newn,    // [B,1,H]
    const float* __restrict__ W1,      // [256,256] row-major [f][n]
    const float* __restrict__ b1,      // [256]
    const float* __restrict__ W2,      // [256,64]
    const float* __restrict__ b2,      // [64]
    const float* __restrict__ W3,      // [64,1]
    const float* __restrict__ b3,      // [1]
    float* __restrict__ out)           // [B*S]
{
    __shared__ float buf[ROWS][FF];    // 32 KB; holds con, then h1

    const int t = threadIdx.x;
    const long row0 = (long)blockIdx.x * ROWS;
    const int b = (int)(row0 >> 12);   // row0 / S

    // ---- stage con tile ----
    // nodes part: 32 rows x 128 floats, fully contiguous in global
    const float4* src = (const float4*)(nodes + (size_t)row0 * HH);
    #pragma unroll
    for (int i = 0; i < 4; ++i) {
        int idx = t + i * 256;         // 0..1023 float4s
        float4 v = src[idx];
        int r  = idx >> 5;             // /32 float4 per row
        int k4 = idx & 31;
        *(float4*)&buf[r][k4 * 4] = v;
    }
    // new_nodes part: broadcast the same 128 values into cols [128,256) of every row
    {
        float nv = newn[b * HH + (t & 127)];
        for (int r = (t >> 7); r < ROWS; r += 2)
            buf[r][HH + (t & 127)] = nv;
    }
    __syncthreads();

    // ---- layer 1: h1 = relu(con @ W1 + b1) ----
    const int c0    = t & 63;          // cols c0, c0+64, c0+128, c0+192
    const int rbase = (t >> 6) * 8;    // 8 rows per thread (uniform per wave)
    float acc[8][4];
    #pragma unroll
    for (int ci = 0; ci < 4; ++ci) {
        float bv = b1[c0 + 64 * ci];
        #pragma unroll
        for (int r = 0; r < 8; ++r) acc[r][ci] = bv;
    }
    for (int k = 0; k < FF; k += 4) {
        float w[4][4];
        #pragma unroll
        for (int kk = 0; kk < 4; ++kk)
            #pragma unroll
            for (int ci = 0; ci < 4; ++ci)
                w[kk][ci] = W1[(k + kk) * N1 + c0 + 64 * ci];
        #pragma unroll
        for (int r = 0; r < 8; ++r) {
            float4 x = *(const float4*)&buf[rbase + r][k];  // wave-broadcast
            #pragma unroll
            for (int ci = 0; ci < 4; ++ci) {
                acc[r][ci] = fmaf(x.x, w[0][ci], acc[r][ci]);
                acc[r][ci] = fmaf(x.y, w[1][ci], acc[r][ci]);
                acc[r][ci] = fmaf(x.z, w[2][ci], acc[r][ci]);
                acc[r][ci] = fmaf(x.w, w[3][ci], acc[r][ci]);
            }
        }
    }
    __syncthreads();                   // everyone done reading con
    #pragma unroll
    for (int r = 0; r < 8; ++r)
        #pragma unroll
        for (int ci = 0; ci < 4; ++ci)
            buf[rbase + r][c0 + 64 * ci] = fmaxf(acc[r][ci], 0.0f);
    __syncthreads();                   // h1 visible

    // ---- layer 2: h2 = relu(h1 @ W2 + b2) ----
    const int c2 = t & 31;             // cols c2, c2+32
    const int g2 = t >> 5;             // 0..7 -> rows 4*g2 .. 4*g2+3
    float acc2[4][2];
    #pragma unroll
    for (int cj = 0; cj < 2; ++cj) {
        float bv = b2[c2 + 32 * cj];
        #pragma unroll
        for (int rr = 0; rr < 4; ++rr) acc2[rr][cj] = bv;
    }
    for (int k = 0; k < FF; k += 4) {
        float w2[4][2];
        #pragma unroll
        for (int kk = 0; kk < 4; ++kk)
            #pragma unroll
            for (int cj = 0; cj < 2; ++cj)
                w2[kk][cj] = W2[(k + kk) * N2 + c2 + 32 * cj];
        #pragma unroll
        for (int rr = 0; rr < 4; ++rr) {
            float4 x = *(const float4*)&buf[4 * g2 + rr][k];  // half-wave broadcast
            #pragma unroll
            for (int cj = 0; cj < 2; ++cj) {
                acc2[rr][cj] = fmaf(x.x, w2[0][cj], acc2[rr][cj]);
                acc2[rr][cj] = fmaf(x.y, w2[1][cj], acc2[rr][cj]);
                acc2[rr][cj] = fmaf(x.z, w2[2][cj], acc2[rr][cj]);
                acc2[rr][cj] = fmaf(x.w, w2[3][cj], acc2[rr][cj]);
            }
        }
    }

    // ---- layer 3: sigmoid(h2 @ W3 + b3) ----
    const float w3a = W3[c2];
    const float w3b = W3[c2 + 32];
    const float bias3 = b3[0];
    float p[4];
    #pragma unroll
    for (int rr = 0; rr < 4; ++rr) {
        float ha = fmaxf(acc2[rr][0], 0.0f);
        float hb = fmaxf(acc2[rr][1], 0.0f);
        p[rr] = fmaf(ha, w3a, hb * w3b);
    }
    // reduce across the 32 lanes holding cols 0..31 (xor<=16 never crosses
    // the 32-lane group boundary inside a 64-lane wave)
    #pragma unroll
    for (int off = 16; off >= 1; off >>= 1)
        #pragma unroll
        for (int rr = 0; rr < 4; ++rr)
            p[rr] += __shfl_xor(p[rr], off, 64);

    if (c2 == 0) {
        #pragma unroll
        for (int rr = 0; rr < 4; ++rr) {
            float v = p[rr] + bias3;
            out[row0 + 4 * g2 + rr] = 1.0f / (1.0f + __expf(-v));
        }
    }
}

extern "C" void kernel_launch(void* const* d_in, const int* in_sizes, int n_in,
                              void* d_out, int out_size, void* d_ws, size_t ws_size,
                              hipStream_t stream) {
    const float* nodes = (const float*)d_in[0];  // [B,S,H]
    const float* newn  = (const float*)d_in[1];  // [B,1,H]
    const float* W1    = (const float*)d_in[2];  // [256,256]
    const float* b1    = (const float*)d_in[3];
    const float* W2    = (const float*)d_in[4];  // [256,64]
    const float* b2    = (const float*)d_in[5];
    const float* W3    = (const float*)d_in[6];  // [64,1]
    const float* b3    = (const float*)d_in[7];
    float* out = (float*)d_out;                  // [B*S] f32

    const int M = BB * SS;                       // 524288 rows
    dim3 grid(M / ROWS), block(256);
    hipLaunchKernelGGL(edge_mlp_f32, grid, block, 0, stream,
                       nodes, newn, W1, b1, W2, b2, W3, b3, out);
}

// Round 2
// 121.989 us; speedup vs baseline: 10.1963x; 10.1963x over previous
//
#include <hip/hip_runtime.h>
#include <hip/hip_bf16.h>
#include <cstdint>
#include <cstddef>

#define BB 128
#define SS 4096
#define HH 128
#define FF 256   // 2*H = K of layer 1
#define N1 256
#define N2 64
#define MROWS 64 // rows per block (64 | S, so one b per block)

typedef __bf16 bf16x8 __attribute__((ext_vector_type(8)));  // 4 VGPRs, MFMA A/B frag
typedef float  f32x4  __attribute__((ext_vector_type(4)));  // MFMA C/D frag

// ---------------------------------------------------------------------------
// Prologue: convert W1 [256][256] f32 and W2 [256][64] f32 into bf16 MFMA
// B-fragment order in ws:  frag[nt][ks][lane][j] = W[32*ks + 8*(lane>>4) + j][16*nt + (lane&15)]
// so the main loop's B-frag load is one coalesced 16B read per lane.
// ---------------------------------------------------------------------------
__global__ __launch_bounds__(256) void conv_weights(
    const float* __restrict__ W1, const float* __restrict__ W2,
    __bf16* __restrict__ w1f, __bf16* __restrict__ w2f)
{
    int tid = blockIdx.x * 256 + threadIdx.x;
    if (tid < 8192) {                       // W1: 16 nt * 8 ks * 64 lanes
        int lane = tid & 63, ks = (tid >> 6) & 7, nt = tid >> 9;
        int col = 16 * nt + (lane & 15);
        int kbase = 32 * ks + 8 * (lane >> 4);
        bf16x8 v;
#pragma unroll
        for (int j = 0; j < 8; ++j) v[j] = (__bf16)W1[(size_t)(kbase + j) * N1 + col];
        *(bf16x8*)(w1f + (size_t)tid * 8) = v;
    } else if (tid < 10240) {               // W2: 4 nt * 8 ks * 64 lanes
        int s = tid - 8192;
        int lane = s & 63, ks = (s >> 6) & 7, nt = s >> 9;
        int col = 16 * nt + (lane & 15);
        int kbase = 32 * ks + 8 * (lane >> 4);
        bf16x8 v;
#pragma unroll
        for (int j = 0; j < 8; ++j) v[j] = (__bf16)W2[(size_t)(kbase + j) * N2 + col];
        *(bf16x8*)(w2f + (size_t)s * 8) = v;
    }
}

// ---------------------------------------------------------------------------
// Main kernel. 256 threads = 4 waves; wave w owns layer-1 cols [64w, 64w+64)
// and layer-2 cols [16w, 16w+16). X (con) staged in LDS in A-frag order with
// XOR swizzle; h1 written back to the same buffer (frag order) after a barrier.
//
// A-frag slot math, tile = mt*8 + ks (16-row m-tile mt, 32-col k-step ks):
//   element (r,k): s = (r&15) + 16*((k>>3)&3), j = k&7
//   physical slot = tile*64 + (s ^ (((s>>3) ^ tile) & 7))   [swizzle]
// Reader (lane l of tile T) uses s = l  -> conflict-free contiguous-ish reads;
// swizzle spreads staging writes (otherwise a 32-way bank conflict).
// ---------------------------------------------------------------------------
__global__ __launch_bounds__(256, 2) void edge_mlp_mfma(
    const float* __restrict__ nodes,   // [B,S,H] f32
    const float* __restrict__ newn,    // [B,1,H] f32
    const float* __restrict__ b1,      // [256]
    const float* __restrict__ b2,      // [64]
    const float* __restrict__ W3,      // [64]
    const float* __restrict__ b3,      // [1]
    const __bf16* __restrict__ w1f,    // W1 frags (prologue)
    const __bf16* __restrict__ w2f,    // W2 frags
    float* __restrict__ out)           // [B*S]
{
    __shared__ uint4 xf[2048];         // 32 KB: X frags, then h1 frags
    __shared__ float red[4][MROWS];    // layer-3 cross-wave partials

    const int t = threadIdx.x;
    const int w = t >> 6;              // wave 0..3
    const int l = t & 63;
    const size_t row0 = (size_t)blockIdx.x * MROWS;
    const int b = (int)(row0 >> 12);   // row0 / S

    // ---- stage con tile as bf16 A-frags ----
#pragma unroll
    for (int i = 0; i < 8; ++i) {
        int idx = i * 256 + t;         // 0..2047 : (row, 8-col chunk)
        int r  = idx >> 5;             // 0..63
        int c8 = idx & 31;             // chunk of 8 cols; k = 8*c8..8*c8+7
        const float* src = (c8 < 16)
            ? (nodes + (row0 + r) * HH + 8 * c8)
            : (newn + (size_t)b * HH + 8 * (c8 - 16));
        float4 f0 = *(const float4*)src;
        float4 f1 = *(const float4*)(src + 4);
        bf16x8 v;
        v[0] = (__bf16)f0.x; v[1] = (__bf16)f0.y; v[2] = (__bf16)f0.z; v[3] = (__bf16)f0.w;
        v[4] = (__bf16)f1.x; v[5] = (__bf16)f1.y; v[6] = (__bf16)f1.z; v[7] = (__bf16)f1.w;
        int tile = (r >> 4) * 8 + (c8 >> 2);
        int s    = (r & 15) + 16 * (c8 & 3);
        int phys = s ^ (((s >> 3) ^ tile) & 7);
        *(bf16x8*)&xf[tile * 64 + phys] = v;
    }
    __syncthreads();

    // ---- layer 1: h1 = relu(X @ W1 + b1), wave w -> cols 64w..64w+63 ----
    f32x4 acc[4][4];                   // [mt][nt]
#pragma unroll
    for (int nt = 0; nt < 4; ++nt) {
        float bv = b1[64 * w + 16 * nt + (l & 15)];
#pragma unroll
        for (int mt = 0; mt < 4; ++mt) {
            acc[mt][nt][0] = bv; acc[mt][nt][1] = bv;
            acc[mt][nt][2] = bv; acc[mt][nt][3] = bv;
        }
    }
#pragma unroll 2
    for (int ks = 0; ks < 8; ++ks) {
        bf16x8 bfrag[4];
#pragma unroll
        for (int nt = 0; nt < 4; ++nt) {
            int slot = ((4 * w + nt) * 8 + ks) * 64 + l;
            bfrag[nt] = *(const bf16x8*)(w1f + (size_t)slot * 8);
        }
#pragma unroll
        for (int mt = 0; mt < 4; ++mt) {
            int tile = mt * 8 + ks;
            int phys = l ^ (((l >> 3) ^ tile) & 7);
            bf16x8 a = *(const bf16x8*)&xf[tile * 64 + phys];
#pragma unroll
            for (int nt = 0; nt < 4; ++nt)
                acc[mt][nt] = __builtin_amdgcn_mfma_f32_16x16x32_bf16(a, bfrag[nt], acc[mt][nt], 0, 0, 0);
        }
    }
    __syncthreads();                   // all waves done reading X frags

    // ---- h1 -> LDS in A-frag order (relu + bf16). C/D: row=(l>>4)*4+reg, col=l&15 ----
#pragma unroll
    for (int mt = 0; mt < 4; ++mt)
#pragma unroll
        for (int nt = 0; nt < 4; ++nt) {
            int c     = 64 * w + 16 * nt + (l & 15);
            int tile2 = mt * 8 + (c >> 5);
            int j2    = c & 7;
            int shi   = (c >> 3) & 3;
#pragma unroll
            for (int reg = 0; reg < 4; ++reg) {
                int s2    = ((l >> 4) * 4 + reg) + 16 * shi;
                int phys2 = s2 ^ (((s2 >> 3) ^ tile2) & 7);
                ((__bf16*)xf)[(tile2 * 64 + phys2) * 8 + j2] =
                    (__bf16)fmaxf(acc[mt][nt][reg], 0.0f);
            }
        }
    __syncthreads();                   // h1 frags visible

    // ---- layer 2: h2 = relu(h1 @ W2 + b2), wave w -> cols 16w..16w+15 ----
    f32x4 acc2[4];
    {
        float bv = b2[16 * w + (l & 15)];
#pragma unroll
        for (int mt = 0; mt < 4; ++mt) {
            acc2[mt][0] = bv; acc2[mt][1] = bv; acc2[mt][2] = bv; acc2[mt][3] = bv;
        }
    }
#pragma unroll 2
    for (int ks = 0; ks < 8; ++ks) {
        int slot = (w * 8 + ks) * 64 + l;
        bf16x8 b2frag = *(const bf16x8*)(w2f + (size_t)slot * 8);
#pragma unroll
        for (int mt = 0; mt < 4; ++mt) {
            int tile = mt * 8 + ks;
            int phys = l ^ (((l >> 3) ^ tile) & 7);
            bf16x8 a = *(const bf16x8*)&xf[tile * 64 + phys];
            acc2[mt] = __builtin_amdgcn_mfma_f32_16x16x32_bf16(a, b2frag, acc2[mt], 0, 0, 0);
        }
    }

    // ---- layer 3: out = sigmoid(relu(h2) @ W3 + b3) ----
    float w3v = W3[16 * w + (l & 15)];
    float pv[4][4];
#pragma unroll
    for (int mt = 0; mt < 4; ++mt)
#pragma unroll
        for (int reg = 0; reg < 4; ++reg)
            pv[mt][reg] = fmaxf(acc2[mt][reg], 0.0f) * w3v;
    // reduce over the wave's 16 cols (l&15); xor<=8 stays in the group
#pragma unroll
    for (int off = 1; off <= 8; off <<= 1)
#pragma unroll
        for (int mt = 0; mt < 4; ++mt)
#pragma unroll
            for (int reg = 0; reg < 4; ++reg)
                pv[mt][reg] += __shfl_xor(pv[mt][reg], off, 64);
    if ((l & 15) == 0) {
#pragma unroll
        for (int mt = 0; mt < 4; ++mt)
#pragma unroll
            for (int reg = 0; reg < 4; ++reg)
                red[w][16 * mt + (l >> 4) * 4 + reg] = pv[mt][reg];
    }
    __syncthreads();
    if (t < MROWS) {
        float v = red[0][t] + red[1][t] + red[2][t] + red[3][t] + b3[0];
        out[row0 + t] = 1.0f / (1.0f + __expf(-v));
    }
}

// ---------------------------------------------------------------------------
// fp32 fallback (round-1 kernel) in case ws_size is too small for weight frags
// ---------------------------------------------------------------------------
__global__ __launch_bounds__(256, 4) void edge_mlp_f32(
    const float* __restrict__ nodes, const float* __restrict__ newn,
    const float* __restrict__ W1, const float* __restrict__ b1,
    const float* __restrict__ W2, const float* __restrict__ b2,
    const float* __restrict__ W3, const float* __restrict__ b3,
    float* __restrict__ out)
{
    __shared__ float buf[32][FF];
    const int t = threadIdx.x;
    const long row0 = (long)blockIdx.x * 32;
    const int b = (int)(row0 >> 12);
    const float4* src = (const float4*)(nodes + (size_t)row0 * HH);
#pragma unroll
    for (int i = 0; i < 4; ++i) {
        int idx = t + i * 256;
        float4 v = src[idx];
        *(float4*)&buf[idx >> 5][(idx & 31) * 4] = v;
    }
    {
        float nv = newn[b * HH + (t & 127)];
        for (int r = (t >> 7); r < 32; r += 2) buf[r][HH + (t & 127)] = nv;
    }
    __syncthreads();
    const int c0 = t & 63, rbase = (t >> 6) * 8;
    float acc[8][4];
#pragma unroll
    for (int ci = 0; ci < 4; ++ci) {
        float bv = b1[c0 + 64 * ci];
#pragma unroll
        for (int r = 0; r < 8; ++r) acc[r][ci] = bv;
    }
    for (int k = 0; k < FF; k += 4) {
        float wv[4][4];
#pragma unroll
        for (int kk = 0; kk < 4; ++kk)
#pragma unroll
            for (int ci = 0; ci < 4; ++ci) wv[kk][ci] = W1[(k + kk) * N1 + c0 + 64 * ci];
#pragma unroll
        for (int r = 0; r < 8; ++r) {
            float4 x = *(const float4*)&buf[rbase + r][k];
#pragma unroll
            for (int ci = 0; ci < 4; ++ci) {
                acc[r][ci] = fmaf(x.x, wv[0][ci], acc[r][ci]);
                acc[r][ci] = fmaf(x.y, wv[1][ci], acc[r][ci]);
                acc[r][ci] = fmaf(x.z, wv[2][ci], acc[r][ci]);
                acc[r][ci] = fmaf(x.w, wv[3][ci], acc[r][ci]);
            }
        }
    }
    __syncthreads();
#pragma unroll
    for (int r = 0; r < 8; ++r)
#pragma unroll
        for (int ci = 0; ci < 4; ++ci) buf[rbase + r][c0 + 64 * ci] = fmaxf(acc[r][ci], 0.0f);
    __syncthreads();
    const int c2 = t & 31, g2 = t >> 5;
    float acc2[4][2];
#pragma unroll
    for (int cj = 0; cj < 2; ++cj) {
        float bv = b2[c2 + 32 * cj];
#pragma unroll
        for (int rr = 0; rr < 4; ++rr) acc2[rr][cj] = bv;
    }
    for (int k = 0; k < FF; k += 4) {
        float w2v[4][2];
#pragma unroll
        for (int kk = 0; kk < 4; ++kk)
#pragma unroll
            for (int cj = 0; cj < 2; ++cj) w2v[kk][cj] = W2[(k + kk) * N2 + c2 + 32 * cj];
#pragma unroll
        for (int rr = 0; rr < 4; ++rr) {
            float4 x = *(const float4*)&buf[4 * g2 + rr][k];
#pragma unroll
            for (int cj = 0; cj < 2; ++cj) {
                acc2[rr][cj] = fmaf(x.x, w2v[0][cj], acc2[rr][cj]);
                acc2[rr][cj] = fmaf(x.y, w2v[1][cj], acc2[rr][cj]);
                acc2[rr][cj] = fmaf(x.z, w2v[2][cj], acc2[rr][cj]);
                acc2[rr][cj] = fmaf(x.w, w2v[3][cj], acc2[rr][cj]);
            }
        }
    }
    const float w3a = W3[c2], w3b = W3[c2 + 32], bias3 = b3[0];
    float p[4];
#pragma unroll
    for (int rr = 0; rr < 4; ++rr)
        p[rr] = fmaf(fmaxf(acc2[rr][0], 0.0f), w3a, fmaxf(acc2[rr][1], 0.0f) * w3b);
#pragma unroll
    for (int off = 16; off >= 1; off >>= 1)
#pragma unroll
        for (int rr = 0; rr < 4; ++rr) p[rr] += __shfl_xor(p[rr], off, 64);
    if (c2 == 0)
#pragma unroll
        for (int rr = 0; rr < 4; ++rr)
            out[row0 + 4 * g2 + rr] = 1.0f / (1.0f + __expf(-(p[rr] + bias3)));
}

extern "C" void kernel_launch(void* const* d_in, const int* in_sizes, int n_in,
                              void* d_out, int out_size, void* d_ws, size_t ws_size,
                              hipStream_t stream) {
    const float* nodes = (const float*)d_in[0];
    const float* newn  = (const float*)d_in[1];
    const float* W1    = (const float*)d_in[2];
    const float* b1    = (const float*)d_in[3];
    const float* W2    = (const float*)d_in[4];
    const float* b2    = (const float*)d_in[5];
    const float* W3    = (const float*)d_in[6];
    const float* b3    = (const float*)d_in[7];
    float* out = (float*)d_out;
    const int M = BB * SS;

    if (ws_size >= 163840) {
        __bf16* w1f = (__bf16*)d_ws;
        __bf16* w2f = (__bf16*)d_ws + 65536;   // 128 KB in
        hipLaunchKernelGGL(conv_weights, dim3(40), dim3(256), 0, stream, W1, W2, w1f, w2f);
        hipLaunchKernelGGL(edge_mlp_mfma, dim3(M / MROWS), dim3(256), 0, stream,
                           nodes, newn, b1, b2, W3, b3, w1f, w2f, out);
    } else {
        hipLaunchKernelGGL(edge_mlp_f32, dim3(M / 32), dim3(256), 0, stream,
                           nodes, newn, W1, b1, W2, b2, W3, b3, out);
    }
}